// Round 2
// baseline (309.286 us; speedup 1.0000x reference)
//
#include <hip/hip_runtime.h>
#include <hip/hip_bf16.h>
#include <stdint.h>

// Problem constants: N=8, CIN=512, COUT=512, K=3, H=W=64
// out = demod[n,co]*sqrt2 * conv(cw, s[n,ci]*x) + nw*noise + bias, leaky(0.2)

typedef __attribute__((ext_vector_type(8))) short short8;
typedef __attribute__((ext_vector_type(4))) float f32x4;
typedef __attribute__((ext_vector_type(4))) unsigned int uint4v;
typedef __attribute__((ext_vector_type(2))) unsigned int uint2v;

__device__ __forceinline__ unsigned short f2bf(float f) {
  unsigned u = __builtin_bit_cast(unsigned, f);
  u += 0x7FFFu + ((u >> 16) & 1u);   // round-to-nearest-even
  return (unsigned short)(u >> 16);
}

__device__ __forceinline__ void g2l16(const void* g, void* l) {
  __builtin_amdgcn_global_load_lds(
      (const __attribute__((address_space(1))) void*)g,
      (__attribute__((address_space(3))) void*)l, 16, 0, 0);
}

// ---------------- k_prep: xpad + s-recompute + demod (0..511) | Wt (512..639)
//                          | halo zero (640..775) --------------------------------
// No cross-block dependencies: s[n,:] and demod[n, h*8..h*8+7] are recomputed
// inside each xpad block from style/mw/cw (all L2/L3-resident), eliminating the
// former k_pre dispatch and the s_buf/wsq global round-trips.
// Xp layout: [n 8][row 66][kb 16][lhi 4][col 66][8] bf16.
// Wt layout: [cb 8][kb 16]{ [tap 9][mt 4][lhi 4][m 16][8] } bf16, tile 36864 B.
__global__ void k_prep(const float* __restrict__ style, const float* __restrict__ mw,
                       const float* __restrict__ mb, const float* __restrict__ cw,
                       const float* __restrict__ x, float* __restrict__ demod_g,
                       unsigned short* __restrict__ Xp, unsigned short* __restrict__ Wt) {
  __shared__ __align__(16) char smem[74240];
  int t = threadIdx.x;
  int b = blockIdx.x;
  if (b < 512) {
    // ---- xpad block (n,h): recompute s[n,:], demod for 8 co's, then pad+pack ----
    int n = b >> 6, h = b & 63;
    short* ldsx = (short*)smem;              // [ci 512][68]  69632 B
    float* sxf  = (float*)(smem + 69632);    // s[n, 0..511]   2048 B
    float* stl  = (float*)(smem + 71680);    // style[n, :]    2048 B (end 73728)
    stl[t] = style[n * 512 + t];
    stl[t + 256] = style[n * 512 + 256 + t];
    __syncthreads();
    // s[n,ci] for ci = t and t+256: serial f32x4 dot vs LDS-broadcast style
#pragma unroll
    for (int rr = 0; rr < 2; ++rr) {
      int ci = t + rr * 256;
      const float* mr = mw + (size_t)ci * 512;
      float a0 = 0.f, a1 = 0.f, a2 = 0.f, a3 = 0.f;
#pragma unroll 8
      for (int k2 = 0; k2 < 128; ++k2) {
        f32x4 wv = *(const f32x4*)(mr + k2 * 4);
        f32x4 sv = *(const f32x4*)(stl + k2 * 4);
        a0 += wv.x * sv.x; a1 += wv.y * sv.y;
        a2 += wv.z * sv.z; a3 += wv.w * sv.w;
      }
      sxf[ci] = (a0 + a1) + (a2 + a3) + mb[ci];
    }
    __syncthreads();
    // demod[n, h*8+g], g = t>>5 (8 groups x 32 lanes); tap-sums direct from cw
    {
      int g = t >> 5, l5 = t & 31;
      int co = h * 8 + g;
      const float* cwb = cw + (size_t)co * 4608;
      float sum = 0.f;
#pragma unroll
      for (int i = 0; i < 16; ++i) {
        int ci = l5 + i * 32;
        const float* p = cwb + ci * 9;
        float a = 0.f;
#pragma unroll
        for (int j = 0; j < 9; ++j) a += p[j] * p[j];
        float sv = sxf[ci];
        sum += sv * sv * a;
      }
#pragma unroll
      for (int off = 16; off; off >>= 1) sum += __shfl_xor(sum, off, 64);
      if (l5 == 0)
        demod_g[n * 512 + co] = rsqrtf(sum + 1e-8f) * 1.41421356237309515f;
    }
    // pad+pack: float4 loads, modulate, bf16 LDS tile, transpose-pack to Xp
    const float* xb = x + ((size_t)n * 512) * 4096 + h * 64;
#pragma unroll
    for (int i = 0; i < 32; ++i) {
      int L = t + i * 256;
      int ci = L >> 4, q = L & 15;
      f32x4 v = *(const f32x4*)(xb + (size_t)ci * 4096 + q * 4);
      float sv = sxf[ci];
      uint2v o;
      o.x = f2bf(v.x * sv) | ((unsigned)f2bf(v.y * sv) << 16);
      o.y = f2bf(v.z * sv) | ((unsigned)f2bf(v.w * sv) << 16);
      *(uint2v*)(ldsx + ci * 68 + q * 4) = o;
    }
    __syncthreads();
    unsigned short* nb = Xp + (size_t)n * 2230272 + (size_t)(h + 1) * 33792;
#pragma unroll
    for (int r = 0; r < 16; ++r) {
      int u = t + r * 256;
      int cig = u >> 6, col = u & 63;   // cig = kb*4+lhi (ci = cig*8+j)
      unsigned v[8];
#pragma unroll
      for (int j = 0; j < 8; ++j)
        v[j] = (unsigned short)ldsx[(cig * 8 + j) * 68 + col];
      uint4v o;
      o.x = v[0] | (v[1] << 16);
      o.y = v[2] | (v[3] << 16);
      o.z = v[4] | (v[5] << 16);
      o.w = v[6] | (v[7] << 16);
      *(uint4v*)(nb + ((size_t)cig * 66 + col + 1) * 8) = o;
    }
  } else if (b < 640) {
    // ---- Wt build: one block per (cb,kb); LDS stride 289 -> conflict-free ----
    int bb = b - 512;
    int cb = bb >> 4, kb = bb & 15;
    float* ldsf = (float*)smem;   // [64][289]  73984 B
#pragma unroll
    for (int i = 0; i < 72; ++i) {
      int idx = t + i * 256;
      int seg = idx / 288, off = idx - seg * 288;
      ldsf[seg * 289 + off] = cw[(size_t)(cb * 64 + seg) * 4608 + kb * 288 + off];
    }
    __syncthreads();
    unsigned short* ob = Wt + (size_t)(cb * 16 + kb) * 18432;
#pragma unroll
    for (int i = 0; i < 9; ++i) {
      int c = t + i * 256;   // chunk 0..2303
      int m = c & 15, lhi = (c >> 4) & 3, mt = (c >> 6) & 3, tap = c >> 8;
      int co_rel = mt * 16 + m;
      unsigned v[8];
#pragma unroll
      for (int j = 0; j < 8; ++j)
        v[j] = f2bf(ldsf[co_rel * 289 + (lhi * 8 + j) * 9 + tap]);
      uint4v o;
      o.x = v[0] | (v[1] << 16);
      o.y = v[2] | (v[3] << 16);
      o.z = v[4] | (v[5] << 16);
      o.w = v[6] | (v[7] << 16);
      *(uint4v*)(ob + (size_t)c * 8) = o;
    }
  } else {
    // ---- halo zero: 16640 16B-chunks per n; 17 parts x 1024 chunks ----
    int bb = b - 640;
    int n = bb / 17, part = bb % 17;
    uint4v z = (uint4v){0u, 0u, 0u, 0u};
    unsigned short* base = Xp + (size_t)n * 2230272;
#pragma unroll
    for (int i = 0; i < 4; ++i) {
      int id = part * 1024 + i * 256 + t;
      if (id < 16640) {
        size_t off;
        if (id < 8448) {                 // rows 0 and 65, full rows
          int row = (id < 4224) ? 0 : 65;
          int c = id - ((id < 4224) ? 0 : 4224);
          off = (size_t)row * 33792 + (size_t)c * 8;
        } else {                         // cols 0 and 65, rows 1..64
          int id2 = id - 8448;
          int row = 1 + (id2 >> 7);
          int rem = id2 & 127;
          int klhi = rem >> 1;
          int col = (rem & 1) ? 65 : 0;
          off = (size_t)row * 33792 + ((size_t)klhi * 66 + col) * 8;
        }
        *(uint4v*)(base + off) = z;
      }
    }
  }
}

// ---------------- k_conv: implicit-GEMM conv (UNCHANGED, verified) ---------------
__global__ void __launch_bounds__(256, 2) k_conv(
    const unsigned short* __restrict__ Wt, const unsigned short* __restrict__ Xp,
    const float* __restrict__ demod, const float* __restrict__ noise,
    const float* __restrict__ nw_p, const float* __restrict__ act_bias,
    float* __restrict__ out) {
  __shared__ short lds_a[18432];   // 36864 B
  __shared__ short lds_x[22528];   // 45056 B (42240 used + staging slack)
  int t = threadIdx.x;
  int r0 = blockIdx.x * 8;
  int cb = blockIdx.y;
  int n = blockIdx.z;
  int lane = t & 63, wv = t >> 6;
  int l15 = lane & 15, lhi = lane >> 4;

  const unsigned short* abase = Wt + (size_t)cb * 16 * 18432;
  const unsigned short* xbase = Xp + (size_t)n * 2230272;
  int xoffg[11];
#pragma unroll
  for (int j = 0; j < 11; ++j) {
    int c = j * 256 + t;
    int r = c / 264, rc = c - r * 264;
    int off = (r0 + r) * 33792 + rc * 8;
    if (c >= 2640) off = 0;
    xoffg[j] = off;
  }

  f32x4 acc[4][8];
#pragma unroll
  for (int a = 0; a < 4; ++a)
#pragma unroll
    for (int bq = 0; bq < 8; ++bq) acc[a][bq] = (f32x4){0.f, 0.f, 0.f, 0.f};

  const int aoff = lhi * 128 + l15 * 8;
  const int xoffb = lhi * 528 + (wv * 16 + l15) * 8;

  for (int kb = 0; kb < 16; ++kb) {
    __syncthreads();
    const char* ab = (const char*)(abase + (size_t)kb * 18432);
#pragma unroll
    for (int i = 0; i < 9; ++i)
      g2l16(ab + i * 4096 + t * 16, (char*)lds_a + i * 4096 + t * 16);
#pragma unroll
    for (int j = 0; j < 11; ++j)
      g2l16(xbase + xoffg[j] + kb * 2112, (char*)lds_x + j * 4096 + t * 16);
    __syncthreads();

#pragma unroll
    for (int dw = 0; dw < 3; ++dw) {
      short8 bf[10];
#pragma unroll
      for (int rr = 0; rr < 10; ++rr)
        bf[rr] = *(const short8*)(lds_x + rr * 2112 + dw * 8 + xoffb);
#pragma unroll
      for (int dh = 0; dh < 3; ++dh) {
#pragma unroll
        for (int mt = 0; mt < 4; ++mt) {
          short8 af = *(const short8*)(lds_a + (dh * 3 + dw) * 2048 + mt * 512 + aoff);
#pragma unroll
          for (int ri = 0; ri < 8; ++ri)
            acc[mt][ri] =
                __builtin_amdgcn_mfma_f32_16x16x32_bf16(af, bf[ri + dh], acc[mt][ri], 0, 0, 0);
        }
      }
    }
  }

  float nw = nw_p[0];
  int col = wv * 16 + l15;
  float nz[8];
#pragma unroll
  for (int ri = 0; ri < 8; ++ri)
    nz[ri] = nw * noise[((size_t)n * 64 + r0 + ri) * 64 + col];
#pragma unroll
  for (int mt = 0; mt < 4; ++mt) {
    f32x4 dm4 = *(const f32x4*)(demod + n * 512 + cb * 64 + mt * 16 + lhi * 4);
#pragma unroll
    for (int c = 0; c < 4; ++c) {
      int co = cb * 64 + mt * 16 + lhi * 4 + c;
      float ab2 = act_bias[co];
      float dm = dm4[c];
#pragma unroll
      for (int ri = 0; ri < 8; ++ri) {
        float v = dm * acc[mt][ri][c] + nz[ri] + ab2;
        v = v > 0.f ? v : 0.2f * v;
        out[(((size_t)n * 512 + co) * 64 + (r0 + ri)) * 64 + col] = v;
      }
    }
  }
}

extern "C" void kernel_launch(void* const* d_in, const int* in_sizes, int n_in,
                              void* d_out, int out_size, void* d_ws, size_t ws_size,
                              hipStream_t stream) {
  const float* x     = (const float*)d_in[0];
  const float* style = (const float*)d_in[1];
  const float* noise = (const float*)d_in[2];
  const float* cw    = (const float*)d_in[3];
  const float* mw    = (const float*)d_in[4];
  const float* mb    = (const float*)d_in[5];
  const float* nw    = (const float*)d_in[6];
  const float* ab    = (const float*)d_in[7];
  float* out = (float*)d_out;

  char* ws = (char*)d_ws;
  float* demod  = (float*)(ws + 16384);                  // 16 KB
  unsigned short* Wt = (unsigned short*)(ws + 1081344);  // 4,718,592 B
  unsigned short* Xp = (unsigned short*)(ws + 5799936);  // 35,684,352 B (end 41.5 MB)

  k_prep<<<776, 256, 0, stream>>>(style, mw, mb, cw, x, demod, Xp, Wt);
  k_conv<<<dim3(8, 8, 8), 256, 0, stream>>>(Wt, Xp, demod, noise, nw, ab, out);
}

// Round 3
// 280.672 us; speedup vs baseline: 1.1020x; 1.1020x over previous
//
#include <hip/hip_runtime.h>
#include <hip/hip_bf16.h>
#include <stdint.h>

// Problem constants: N=8, CIN=512, COUT=512, K=3, H=W=64
// out = demod[n,co]*sqrt2 * conv(cw, s[n,ci]*x) + nw*noise + bias, leaky(0.2)

typedef __attribute__((ext_vector_type(8))) short short8;
typedef __attribute__((ext_vector_type(4))) float f32x4;
typedef __attribute__((ext_vector_type(4))) unsigned int uint4v;
typedef __attribute__((ext_vector_type(2))) unsigned int uint2v;

__device__ __forceinline__ unsigned short f2bf(float f) {
  unsigned u = __builtin_bit_cast(unsigned, f);
  u += 0x7FFFu + ((u >> 16) & 1u);   // round-to-nearest-even
  return (unsigned short)(u >> 16);
}

__device__ __forceinline__ void g2l16(const void* g, void* l) {
  __builtin_amdgcn_global_load_lds(
      (const __attribute__((address_space(1))) void*)g,
      (__attribute__((address_space(3))) void*)l, 16, 0, 0);
}

// ---------------- k_prep: xpad + s + demod (0..511) | Wt (512..639)
//                          | halo zero (640..775) --------------------------------
// 2-dispatch structure (each dispatch boundary costs >=42 us in this harness).
// s[n,:] recomputed per xpad block COOPERATIVELY: lanes index k (coalesced
// 16 B/lane contiguous), 16-lane groups, 4 ci in flight per wave. This replaces
// R2's serial per-thread dot (16B/lane at 2KB stride - the R2 regression).
// Xp layout: [n 8][row 66][kb 16][lhi 4][col 66][8] bf16.
// Wt layout: [cb 8][kb 16]{ [tap 9][mt 4][lhi 4][m 16][8] } bf16, tile 36864 B.
__global__ void k_prep(const float* __restrict__ style, const float* __restrict__ mw,
                       const float* __restrict__ mb, const float* __restrict__ cw,
                       const float* __restrict__ x, float* __restrict__ demod_g,
                       unsigned short* __restrict__ Xp, unsigned short* __restrict__ Wt) {
  __shared__ __align__(16) char smem[74240];
  int t = threadIdx.x;
  int b = blockIdx.x;
  if (b < 512) {
    // ---- xpad block (n,h): s[n,:] cooperative, demod for 8 co's, pad+pack ----
    int n = b >> 6, h = b & 63;
    short* ldsx = (short*)smem;              // [ci 512][68]  69632 B
    float* sxf  = (float*)(smem + 69632);    // s[n, 0..511]   2048 B
    float* stl  = (float*)(smem + 71680);    // style[n, :]    2048 B (end 73728)
    stl[t] = style[n * 512 + t];
    stl[t + 256] = style[n * 512 + 256 + t];
    __syncthreads();
    // s[n,ci]: wave wv covers ci = wv*128..+127; 16-lane groups, lanes along k.
    {
      int lane = t & 63, wv = t >> 6;
      int g = lane >> 4, l = lane & 15;
#pragma unroll 2
      for (int cr = 0; cr < 32; ++cr) {
        int ci = wv * 128 + cr * 4 + g;
        const float* mr = mw + (size_t)ci * 512;
        float sum = 0.f;
#pragma unroll
        for (int it = 0; it < 8; ++it) {
          f32x4 a = *(const f32x4*)(mr + l * 4 + it * 64);
          f32x4 sv = *(const f32x4*)(stl + l * 4 + it * 64);
          sum += a.x * sv.x + a.y * sv.y + a.z * sv.z + a.w * sv.w;
        }
        sum += __shfl_xor(sum, 1, 64);
        sum += __shfl_xor(sum, 2, 64);
        sum += __shfl_xor(sum, 4, 64);
        sum += __shfl_xor(sum, 8, 64);
        if (l == 0) sxf[ci] = sum + mb[ci];
      }
    }
    __syncthreads();
    // demod[n, h*8+g], g = t>>5 (8 groups x 32 lanes); tap-sums direct from cw
    {
      int g = t >> 5, l5 = t & 31;
      int co = h * 8 + g;
      const float* cwb = cw + (size_t)co * 4608;
      float sum = 0.f;
#pragma unroll
      for (int i = 0; i < 16; ++i) {
        int ci = l5 + i * 32;
        const float* p = cwb + ci * 9;
        float a = 0.f;
#pragma unroll
        for (int j = 0; j < 9; ++j) a += p[j] * p[j];
        float sv = sxf[ci];
        sum += sv * sv * a;
      }
#pragma unroll
      for (int off = 16; off; off >>= 1) sum += __shfl_xor(sum, off, 64);
      if (l5 == 0)
        demod_g[n * 512 + co] = rsqrtf(sum + 1e-8f) * 1.41421356237309515f;
    }
    // pad+pack: float4 loads, modulate, bf16 LDS tile, transpose-pack to Xp
    const float* xb = x + ((size_t)n * 512) * 4096 + h * 64;
#pragma unroll
    for (int i = 0; i < 32; ++i) {
      int L = t + i * 256;
      int ci = L >> 4, q = L & 15;
      f32x4 v = *(const f32x4*)(xb + (size_t)ci * 4096 + q * 4);
      float sv = sxf[ci];
      uint2v o;
      o.x = f2bf(v.x * sv) | ((unsigned)f2bf(v.y * sv) << 16);
      o.y = f2bf(v.z * sv) | ((unsigned)f2bf(v.w * sv) << 16);
      *(uint2v*)(ldsx + ci * 68 + q * 4) = o;
    }
    __syncthreads();
    unsigned short* nb = Xp + (size_t)n * 2230272 + (size_t)(h + 1) * 33792;
#pragma unroll
    for (int r = 0; r < 16; ++r) {
      int u = t + r * 256;
      int cig = u >> 6, col = u & 63;   // cig = kb*4+lhi (ci = cig*8+j)
      unsigned v[8];
#pragma unroll
      for (int j = 0; j < 8; ++j)
        v[j] = (unsigned short)ldsx[(cig * 8 + j) * 68 + col];
      uint4v o;
      o.x = v[0] | (v[1] << 16);
      o.y = v[2] | (v[3] << 16);
      o.z = v[4] | (v[5] << 16);
      o.w = v[6] | (v[7] << 16);
      *(uint4v*)(nb + ((size_t)cig * 66 + col + 1) * 8) = o;
    }
  } else if (b < 640) {
    // ---- Wt build: one block per (cb,kb); LDS stride 289 -> conflict-free ----
    int bb = b - 512;
    int cb = bb >> 4, kb = bb & 15;
    float* ldsf = (float*)smem;   // [64][289]  73984 B... fits in 74240
#pragma unroll
    for (int i = 0; i < 72; ++i) {
      int idx = t + i * 256;
      int seg = idx / 288, off = idx - seg * 288;
      ldsf[seg * 289 + off] = cw[(size_t)(cb * 64 + seg) * 4608 + kb * 288 + off];
    }
    __syncthreads();
    unsigned short* ob = Wt + (size_t)(cb * 16 + kb) * 18432;
#pragma unroll
    for (int i = 0; i < 9; ++i) {
      int c = t + i * 256;   // chunk 0..2303
      int m = c & 15, lhi = (c >> 4) & 3, mt = (c >> 6) & 3, tap = c >> 8;
      int co_rel = mt * 16 + m;
      unsigned v[8];
#pragma unroll
      for (int j = 0; j < 8; ++j)
        v[j] = f2bf(ldsf[co_rel * 289 + (lhi * 8 + j) * 9 + tap]);
      uint4v o;
      o.x = v[0] | (v[1] << 16);
      o.y = v[2] | (v[3] << 16);
      o.z = v[4] | (v[5] << 16);
      o.w = v[6] | (v[7] << 16);
      *(uint4v*)(ob + (size_t)c * 8) = o;
    }
  } else {
    // ---- halo zero: 16640 16B-chunks per n; 17 parts x 1024 chunks ----
    int bb = b - 640;
    int n = bb / 17, part = bb % 17;
    uint4v z = (uint4v){0u, 0u, 0u, 0u};
    unsigned short* base = Xp + (size_t)n * 2230272;
#pragma unroll
    for (int i = 0; i < 4; ++i) {
      int id = part * 1024 + i * 256 + t;
      if (id < 16640) {
        size_t off;
        if (id < 8448) {                 // rows 0 and 65, full rows
          int row = (id < 4224) ? 0 : 65;
          int c = id - ((id < 4224) ? 0 : 4224);
          off = (size_t)row * 33792 + (size_t)c * 8;
        } else {                         // cols 0 and 65, rows 1..64
          int id2 = id - 8448;
          int row = 1 + (id2 >> 7);
          int rem = id2 & 127;
          int klhi = rem >> 1;
          int col = (rem & 1) ? 65 : 0;
          off = (size_t)row * 33792 + ((size_t)klhi * 66 + col) * 8;
        }
        *(uint4v*)(base + off) = z;
      }
    }
  }
}

// ---------------- k_conv: implicit-GEMM conv (UNCHANGED, verified) ---------------
__global__ void __launch_bounds__(256, 2) k_conv(
    const unsigned short* __restrict__ Wt, const unsigned short* __restrict__ Xp,
    const float* __restrict__ demod, const float* __restrict__ noise,
    const float* __restrict__ nw_p, const float* __restrict__ act_bias,
    float* __restrict__ out) {
  __shared__ short lds_a[18432];   // 36864 B
  __shared__ short lds_x[22528];   // 45056 B (42240 used + staging slack)
  int t = threadIdx.x;
  int r0 = blockIdx.x * 8;
  int cb = blockIdx.y;
  int n = blockIdx.z;
  int lane = t & 63, wv = t >> 6;
  int l15 = lane & 15, lhi = lane >> 4;

  const unsigned short* abase = Wt + (size_t)cb * 16 * 18432;
  const unsigned short* xbase = Xp + (size_t)n * 2230272;
  int xoffg[11];
#pragma unroll
  for (int j = 0; j < 11; ++j) {
    int c = j * 256 + t;
    int r = c / 264, rc = c - r * 264;
    int off = (r0 + r) * 33792 + rc * 8;
    if (c >= 2640) off = 0;
    xoffg[j] = off;
  }

  f32x4 acc[4][8];
#pragma unroll
  for (int a = 0; a < 4; ++a)
#pragma unroll
    for (int bq = 0; bq < 8; ++bq) acc[a][bq] = (f32x4){0.f, 0.f, 0.f, 0.f};

  const int aoff = lhi * 128 + l15 * 8;
  const int xoffb = lhi * 528 + (wv * 16 + l15) * 8;

  for (int kb = 0; kb < 16; ++kb) {
    __syncthreads();
    const char* ab = (const char*)(abase + (size_t)kb * 18432);
#pragma unroll
    for (int i = 0; i < 9; ++i)
      g2l16(ab + i * 4096 + t * 16, (char*)lds_a + i * 4096 + t * 16);
#pragma unroll
    for (int j = 0; j < 11; ++j)
      g2l16(xbase + xoffg[j] + kb * 2112, (char*)lds_x + j * 4096 + t * 16);
    __syncthreads();

#pragma unroll
    for (int dw = 0; dw < 3; ++dw) {
      short8 bf[10];
#pragma unroll
      for (int rr = 0; rr < 10; ++rr)
        bf[rr] = *(const short8*)(lds_x + rr * 2112 + dw * 8 + xoffb);
#pragma unroll
      for (int dh = 0; dh < 3; ++dh) {
#pragma unroll
        for (int mt = 0; mt < 4; ++mt) {
          short8 af = *(const short8*)(lds_a + (dh * 3 + dw) * 2048 + mt * 512 + aoff);
#pragma unroll
          for (int ri = 0; ri < 8; ++ri)
            acc[mt][ri] =
                __builtin_amdgcn_mfma_f32_16x16x32_bf16(af, bf[ri + dh], acc[mt][ri], 0, 0, 0);
        }
      }
    }
  }

  float nw = nw_p[0];
  int col = wv * 16 + l15;
  float nz[8];
#pragma unroll
  for (int ri = 0; ri < 8; ++ri)
    nz[ri] = nw * noise[((size_t)n * 64 + r0 + ri) * 64 + col];
#pragma unroll
  for (int mt = 0; mt < 4; ++mt) {
    f32x4 dm4 = *(const f32x4*)(demod + n * 512 + cb * 64 + mt * 16 + lhi * 4);
#pragma unroll
    for (int c = 0; c < 4; ++c) {
      int co = cb * 64 + mt * 16 + lhi * 4 + c;
      float ab2 = act_bias[co];
      float dm = dm4[c];
#pragma unroll
      for (int ri = 0; ri < 8; ++ri) {
        float v = dm * acc[mt][ri][c] + nz[ri] + ab2;
        v = v > 0.f ? v : 0.2f * v;
        out[(((size_t)n * 512 + co) * 64 + (r0 + ri)) * 64 + col] = v;
      }
    }
  }
}

extern "C" void kernel_launch(void* const* d_in, const int* in_sizes, int n_in,
                              void* d_out, int out_size, void* d_ws, size_t ws_size,
                              hipStream_t stream) {
  const float* x     = (const float*)d_in[0];
  const float* style = (const float*)d_in[1];
  const float* noise = (const float*)d_in[2];
  const float* cw    = (const float*)d_in[3];
  const float* mw    = (const float*)d_in[4];
  const float* mb    = (const float*)d_in[5];
  const float* nw    = (const float*)d_in[6];
  const float* ab    = (const float*)d_in[7];
  float* out = (float*)d_out;

  char* ws = (char*)d_ws;
  float* demod  = (float*)(ws + 16384);                  // 16 KB
  unsigned short* Wt = (unsigned short*)(ws + 1081344);  // 4,718,592 B
  unsigned short* Xp = (unsigned short*)(ws + 5799936);  // 35,684,352 B (end 41.5 MB)

  k_prep<<<776, 256, 0, stream>>>(style, mw, mb, cw, x, demod, Xp, Wt);
  k_conv<<<dim3(8, 8, 8), 256, 0, stream>>>(Wt, Xp, demod, noise, nw, ab, out);
}